// Round 3
// baseline (273.566 us; speedup 1.0000x reference)
//
#include <hip/hip_runtime.h>
#include <math.h>

#define LRELU_ALPHA 0.2f
#define NEG_INF -1000000000.0f

constexpr int B_ = 8, N_ = 2048, FIN = 128, FOUT = 64;

typedef __attribute__((ext_vector_type(8))) short bf16x8;  // MFMA A/B frag (4 VGPR)
typedef __attribute__((ext_vector_type(4))) float f32x4;   // MFMA C/D frag

// ---------------------------------------------------------------------------
// Kernel 1: Wh = h @ W^T (fp32), emitted as split-bf16 transposed WhT_hi/lo
// [b][o][n]; also s1 = Wh@a1, s2 = Wh@a2. (~3-6 us, not the bottleneck)
// ---------------------------------------------------------------------------
__global__ __launch_bounds__(256) void k_wh(
    const float* __restrict__ h, const float* __restrict__ W,
    const float* __restrict__ a,
    unsigned short* __restrict__ WhT_hi, unsigned short* __restrict__ WhT_lo,
    float* __restrict__ s1, float* __restrict__ s2) {
  __shared__ float Wt[128][65];  // [f][o]: read bank (f+o)%32 -> conflict-free
  __shared__ float hs[16][128];

  const int t = threadIdx.x;
  const int row0 = blockIdx.x * 16;

  for (int e = t; e < 64 * 128; e += 256) {
    int o = e >> 7, f = e & 127;
    Wt[f][o] = W[e];
  }
  {
    const float4* hg = (const float4*)(h + (size_t)row0 * FIN);
    for (int i4 = t; i4 < 16 * 32; i4 += 256) {
      int r = i4 >> 5, f4 = i4 & 31;
      *(float4*)&hs[r][f4 * 4] = hg[i4];
    }
  }
  __syncthreads();

  const int wave = t >> 6, lane = t & 63;  // lane = o
  float acc[4] = {0.f, 0.f, 0.f, 0.f};
#pragma unroll 4
  for (int f4 = 0; f4 < 32; ++f4) {
    float w0 = Wt[4 * f4 + 0][lane], w1 = Wt[4 * f4 + 1][lane];
    float w2 = Wt[4 * f4 + 2][lane], w3 = Wt[4 * f4 + 3][lane];
#pragma unroll
    for (int r = 0; r < 4; ++r) {
      float4 hv = *(const float4*)&hs[wave * 4 + r][f4 * 4];
      acc[r] += hv.x * w0 + hv.y * w1 + hv.z * w2 + hv.w * w3;
    }
  }

  const float a1v = a[lane], a2v = a[64 + lane];
  const int b = row0 / N_;
#pragma unroll
  for (int r = 0; r < 4; ++r) {
    const int row = row0 + wave * 4 + r;
    const int n = row - b * N_;
    const float v = acc[r];
    unsigned int u = __float_as_uint(v) & 0xFFFF0000u;
    float lo = v - __uint_as_float(u);  // exact
    size_t base = ((size_t)b * 64 + lane) * N_ + n;
    WhT_hi[base] = (unsigned short)(u >> 16);
    WhT_lo[base] = (unsigned short)(__float_as_uint(lo) >> 16);
    float p1 = v * a1v, p2 = v * a2v;
#pragma unroll
    for (int d = 32; d; d >>= 1) {
      p1 += __shfl_xor(p1, d, 64);
      p2 += __shfl_xor(p2, d, 64);
    }
    if (lane == 0) { s1[row] = p1; s2[row] = p2; }
  }
}

// ---------------------------------------------------------------------------
// Kernel 2: masked softmax + att@Wh via MFMA 16x16x32 bf16 split hi/lo.
// R3: explicit 2-stage software pipeline. Per K-chunk (32 j):
//   1. issue next chunk's adj+s2 loads (HBM stream, longest latency)
//   2. issue all 8 WhT fragment loads for this chunk (L2-resident)
//   3. exp/pack VALU block on already-resident adj (covers WhT latency)
//   4. 12 MFMA
// cur/next register sets keep ~10 loads in flight per wave; at 16 waves/CU
// that is enough MLP to stream adj near HBM rate. No barriers in K-loop.
// ---------------------------------------------------------------------------
__global__ __launch_bounds__(256, 4) void k_attn(
    const unsigned short* __restrict__ WhT_hi,
    const unsigned short* __restrict__ WhT_lo,
    const float* __restrict__ s1g, const float* __restrict__ s2g,
    const int* __restrict__ adj, float* __restrict__ out) {
  __shared__ float acc_lds[4][64][17];  // pad 17: write stride odd -> 2-way max
  __shared__ float lsum_lds[4][16];

  const int t = threadIdx.x;
  const int wave = t >> 6, lane = t & 63;
  const int b = blockIdx.y;
  const int i0 = blockIdx.x * 16;
  const int m = lane & 15, q = lane >> 4;

  const float s1r = s1g[b * N_ + i0 + m];
  const int jbase = wave * (N_ / 4);  // this wave's 512-j quarter
  const int* adjR = adj + ((size_t)b * N_ + i0 + m) * (size_t)N_;
  const float* s2R = s2g + b * N_;
  const unsigned short* whh = WhT_hi + (size_t)b * 64 * N_;
  const unsigned short* whl = WhT_lo + (size_t)b * 64 * N_;

  f32x4 acc0 = {0.f, 0.f, 0.f, 0.f}, acc1 = acc0, acc2 = acc0, acc3 = acc0;
  float lsum = 0.f;

  // Prologue: chunk 0 adj + s2 into the 'cur' set.
  int4 ca0 = *(const int4*)(adjR + jbase + q * 8);
  int4 ca1 = *(const int4*)(adjR + jbase + q * 8 + 4);
  float4 cs0 = *(const float4*)(s2R + jbase + q * 8);
  float4 cs1 = *(const float4*)(s2R + jbase + q * 8 + 4);

  for (int c = 0; c < 16; ++c) {
    const int jq = jbase + c * 32 + q * 8;

    // (1) prefetch next chunk's adj/s2 (clamped reload on last iter: harmless)
    const int jqn = jbase + (c < 15 ? c + 1 : c) * 32 + q * 8;
    int4 na0 = *(const int4*)(adjR + jqn);
    int4 na1 = *(const int4*)(adjR + jqn + 4);
    float4 ns0 = *(const float4*)(s2R + jqn);
    float4 ns1 = *(const float4*)(s2R + jqn + 4);

    // (2) all 8 WhT fragment loads for this chunk, issued together
    const size_t o0 = (size_t)m * N_ + jq;
    bf16x8 bh0 = *(const bf16x8*)(whh + o0);
    bf16x8 bl0 = *(const bf16x8*)(whl + o0);
    bf16x8 bh1 = *(const bf16x8*)(whh + o0 + 16 * N_);
    bf16x8 bl1 = *(const bf16x8*)(whl + o0 + 16 * N_);
    bf16x8 bh2 = *(const bf16x8*)(whh + o0 + 32 * N_);
    bf16x8 bl2 = *(const bf16x8*)(whl + o0 + 32 * N_);
    bf16x8 bh3 = *(const bf16x8*)(whh + o0 + 48 * N_);
    bf16x8 bl3 = *(const bf16x8*)(whl + o0 + 48 * N_);

    // (3) exp + split-bf16 pack on the resident 'cur' adj/s2
    float xs[8] = {cs0.x, cs0.y, cs0.z, cs0.w, cs1.x, cs1.y, cs1.z, cs1.w};
    int avs[8] = {ca0.x, ca0.y, ca0.z, ca0.w, ca1.x, ca1.y, ca1.z, ca1.w};
    bf16x8 ah, al;
#pragma unroll
    for (int j = 0; j < 8; ++j) {
      float x = s1r + xs[j];
      float e = fmaxf(x, LRELU_ALPHA * x);
      e = avs[j] ? e : NEG_INF;
      float p = __expf(e);  // masked -> exactly 0.0f
      lsum += p;
      unsigned int u = __float_as_uint(p) & 0xFFFF0000u;
      ah[j] = (short)(u >> 16);
      float lo = p - __uint_as_float(u);  // exact
      al[j] = (short)(__float_as_uint(lo) >> 16);
    }

    // (4) MFMA: D += Ah*Bh + Ah*Bl + Al*Bh  (repr error ~2^-16)
    acc0 = __builtin_amdgcn_mfma_f32_16x16x32_bf16(ah, bh0, acc0, 0, 0, 0);
    acc1 = __builtin_amdgcn_mfma_f32_16x16x32_bf16(ah, bh1, acc1, 0, 0, 0);
    acc2 = __builtin_amdgcn_mfma_f32_16x16x32_bf16(ah, bh2, acc2, 0, 0, 0);
    acc3 = __builtin_amdgcn_mfma_f32_16x16x32_bf16(ah, bh3, acc3, 0, 0, 0);
    acc0 = __builtin_amdgcn_mfma_f32_16x16x32_bf16(ah, bl0, acc0, 0, 0, 0);
    acc1 = __builtin_amdgcn_mfma_f32_16x16x32_bf16(ah, bl1, acc1, 0, 0, 0);
    acc2 = __builtin_amdgcn_mfma_f32_16x16x32_bf16(ah, bl2, acc2, 0, 0, 0);
    acc3 = __builtin_amdgcn_mfma_f32_16x16x32_bf16(ah, bl3, acc3, 0, 0, 0);
    acc0 = __builtin_amdgcn_mfma_f32_16x16x32_bf16(al, bh0, acc0, 0, 0, 0);
    acc1 = __builtin_amdgcn_mfma_f32_16x16x32_bf16(al, bh1, acc1, 0, 0, 0);
    acc2 = __builtin_amdgcn_mfma_f32_16x16x32_bf16(al, bh2, acc2, 0, 0, 0);
    acc3 = __builtin_amdgcn_mfma_f32_16x16x32_bf16(al, bh3, acc3, 0, 0, 0);

    // rotate pipeline registers
    ca0 = na0; ca1 = na1; cs0 = ns0; cs1 = ns1;
  }

  // lsum: sum the 4 q-lanes sharing row m
  lsum += __shfl_xor(lsum, 16, 64);
  lsum += __shfl_xor(lsum, 32, 64);
  if (lane < 16) lsum_lds[wave][lane] = lsum;

  {
    float av[16] = {acc0.x, acc0.y, acc0.z, acc0.w, acc1.x, acc1.y, acc1.z,
                    acc1.w, acc2.x, acc2.y, acc2.z, acc2.w, acc3.x, acc3.y,
                    acc3.z, acc3.w};
#pragma unroll
    for (int s = 0; s < 16; ++s) acc_lds[wave][lane][s] = av[s];
  }
  __syncthreads();  // the only barrier

  // Merge 4 wave-partials; C/D layout: row = (lane>>4)*4 + reg, col = lane&15
#pragma unroll
  for (int kk = 0; kk < 4; ++kk) {
    int e = kk * 256 + t;
    int row = e >> 6, o = e & 63;
    int src_lane = (o & 15) | ((row >> 2) << 4);
    int slot = (o >> 4) * 4 + (row & 3);
    float v = acc_lds[0][src_lane][slot] + acc_lds[1][src_lane][slot] +
              acc_lds[2][src_lane][slot] + acc_lds[3][src_lane][slot];
    float l = lsum_lds[0][row] + lsum_lds[1][row] +
              lsum_lds[2][row] + lsum_lds[3][row];
    if (l == 0.f) l = 1.f;  // fully-masked row guard
    out[((size_t)b * N_ + i0 + row) * FOUT + o] = v / l;
  }
}

extern "C" void kernel_launch(void* const* d_in, const int* in_sizes, int n_in,
                              void* d_out, int out_size, void* d_ws, size_t ws_size,
                              hipStream_t stream) {
  const float* h   = (const float*)d_in[0];
  const int*   adj = (const int*)d_in[1];
  const float* W   = (const float*)d_in[2];
  const float* a   = (const float*)d_in[3];
  float* out = (float*)d_out;

  unsigned short* WhT_hi = (unsigned short*)d_ws;
  unsigned short* WhT_lo = WhT_hi + (size_t)B_ * 64 * N_;
  float* s1 = (float*)(WhT_lo + (size_t)B_ * 64 * N_);
  float* s2 = s1 + (size_t)B_ * N_;

  k_wh<<<dim3(B_ * N_ / 16), 256, 0, stream>>>(h, W, a, WhT_hi, WhT_lo, s1, s2);
  k_attn<<<dim3(N_ / 16, B_), 256, 0, stream>>>(WhT_hi, WhT_lo, s1, s2, adj, out);
}

// Round 4
// 226.209 us; speedup vs baseline: 1.2093x; 1.2093x over previous
//
#include <hip/hip_runtime.h>
#include <hip/hip_fp16.h>
#include <math.h>

#define LRELU_ALPHA 0.2f
#define NEG_INF -1000000000.0f

constexpr int B_ = 8, N_ = 2048, FIN = 128, FOUT = 64;

typedef _Float16 __attribute__((ext_vector_type(8))) f16x8;
typedef float __attribute__((ext_vector_type(4))) f32x4;

// async global->LDS, 16B per lane; lane l's data lands at ldsbase + l*16
__device__ __forceinline__ void gload16(const void* g, void* l) {
  __builtin_amdgcn_global_load_lds(
      (const __attribute__((address_space(1))) void*)g,
      (__attribute__((address_space(3))) void*)l, 16, 0, 0);
}

// ---------------------------------------------------------------------------
// Kernel 1: Wh = h @ W^T (fp32), emitted as fp16 transposed WhT[b][o][n];
// also s1 = Wh@a1, s2 = Wh@a2 (fp32).
// ---------------------------------------------------------------------------
__global__ __launch_bounds__(256) void k_wh(
    const float* __restrict__ h, const float* __restrict__ W,
    const float* __restrict__ a, unsigned short* __restrict__ WhT,
    float* __restrict__ s1, float* __restrict__ s2) {
  __shared__ float Wt[128][65];  // [f][o]: read bank (f+o)%32 -> conflict-free
  __shared__ float hs[16][128];

  const int t = threadIdx.x;
  const int row0 = blockIdx.x * 16;

  for (int e = t; e < 64 * 128; e += 256) {
    int o = e >> 7, f = e & 127;
    Wt[f][o] = W[e];
  }
  {
    const float4* hg = (const float4*)(h + (size_t)row0 * FIN);
    for (int i4 = t; i4 < 16 * 32; i4 += 256) {
      int r = i4 >> 5, f4 = i4 & 31;
      *(float4*)&hs[r][f4 * 4] = hg[i4];
    }
  }
  __syncthreads();

  const int wave = t >> 6, lane = t & 63;  // lane = o
  float acc[4] = {0.f, 0.f, 0.f, 0.f};
#pragma unroll 4
  for (int f4 = 0; f4 < 32; ++f4) {
    float w0 = Wt[4 * f4 + 0][lane], w1 = Wt[4 * f4 + 1][lane];
    float w2 = Wt[4 * f4 + 2][lane], w3 = Wt[4 * f4 + 3][lane];
#pragma unroll
    for (int r = 0; r < 4; ++r) {
      float4 hv = *(const float4*)&hs[wave * 4 + r][f4 * 4];
      acc[r] += hv.x * w0 + hv.y * w1 + hv.z * w2 + hv.w * w3;
    }
  }

  const float a1v = a[lane], a2v = a[64 + lane];
  const int b = row0 / N_;
#pragma unroll
  for (int r = 0; r < 4; ++r) {
    const int row = row0 + wave * 4 + r;
    const int n = row - b * N_;
    const float v = acc[r];
    WhT[((size_t)b * 64 + lane) * N_ + n] = __half_as_ushort(__float2half(v));
    float p1 = v * a1v, p2 = v * a2v;
#pragma unroll
    for (int d = 32; d; d >>= 1) {
      p1 += __shfl_xor(p1, d, 64);
      p2 += __shfl_xor(p2, d, 64);
    }
    if (lane == 0) { s1[row] = p1; s2[row] = p2; }
  }
}

// ---------------------------------------------------------------------------
// Kernel 2: masked softmax + att@Wh, async-LDS pipelined, fp16 MFMA.
// Block = 32 i-rows x 64 o; K-loop chunks of 64 j. Per chunk 16 KB staged by
// 16 global_load_lds_dwordx4 (adj[32][64] int + WhT[64][64] fp16), spread 4
// per wave. Wave w consumes tile (rowgrp = w&1, o-groups {p0,p0+1}) -> full
// accumulation per wave, no cross-wave merge. p = exp(lrelu(s1+s2) - 2):
// the -2 shift keeps p in fp16 range (num & denom scale identically).
// Double buffers sA/sB are distinct __shared__ objects so chunk c+1's DMA
// provably doesn't alias chunk c's ds_reads.
// ---------------------------------------------------------------------------
__global__ __launch_bounds__(256, 2) void k_attn(
    const unsigned short* __restrict__ WhT,
    const float* __restrict__ s1g, const float* __restrict__ s2g,
    const int* __restrict__ adj, float* __restrict__ out) {
  __shared__ __align__(16) unsigned char sA[16 * 1024];
  __shared__ __align__(16) unsigned char sB[16 * 1024];
  __shared__ float s2s[N_];
  __shared__ float lsum_lds[32];

  const int t = threadIdx.x;
  const int wave = t >> 6, lane = t & 63;
  const int m = lane & 15, q = lane >> 4;
  const int b = blockIdx.y;
  const int i0 = blockIdx.x * 32;
  const int rg = wave & 1;          // this wave's row-group (rows rg*16..+16)
  const int p0 = (wave >> 1) * 2;   // this wave's first o-group

  const int* adjB = adj + (size_t)b * N_ * N_;
  const unsigned short* whB = WhT + (size_t)b * 64 * N_;
  const float* s2R = s2g + b * N_;

  // preload the full s2 row-block (8 KB)
  for (int i = t; i < N_ / 4; i += 256)
    ((float4*)s2s)[i] = ((const float4*)s2R)[i];

  const float s1r = s1g[b * N_ + i0 + rg * 16 + m];

  // per-wave staging sources (4 DMA instrs per wave per chunk):
  //  waves 0,1: adj rows rg*16..+16, instr ii -> (ks=ii>>1, h=ii&1)
  //  waves 2,3: WhT,               instr ii -> (g=(w-2)*2+(ii>>1), ks=ii&1)
  // LDS slot layout: instr idx*1024 + lane*16, where
  //  adj idx = rg*4 + ks*2 + h ; WhT idx = 8 + g*2 + ks
  const unsigned char* gp[4];
  int gstr;
  if (wave < 2) {
    const size_t r = (size_t)(i0 + wave * 16 + m);
#pragma unroll
    for (int ii = 0; ii < 4; ++ii) {
      int ks = ii >> 1, hh = ii & 1;
      gp[ii] = (const unsigned char*)(adjB + r * N_ + ks * 32 + q * 8 + hh * 4);
    }
    gstr = 64 * 4;   // 64 ints per chunk
  } else {
#pragma unroll
    for (int ii = 0; ii < 4; ++ii) {
      int g = (wave - 2) * 2 + (ii >> 1), ks = ii & 1;
      gp[ii] = (const unsigned char*)(whB + (size_t)(g * 16 + m) * N_ +
                                      ks * 32 + q * 8);
    }
    gstr = 64 * 2;   // 64 fp16 per chunk
  }

#define STAGE(S, c)                                                       \
  {                                                                       \
    _Pragma("unroll") for (int ii = 0; ii < 4; ++ii)                      \
        gload16(gp[ii] + (size_t)(c) * gstr, (S) + (wave * 4 + ii) * 1024); \
  }

  f32x4 acc0 = {0.f, 0.f, 0.f, 0.f}, acc1 = acc0;
  float lsum = 0.f;

  auto consume = [&](const unsigned char* base, int c) {
#pragma unroll
    for (int ks = 0; ks < 2; ++ks) {
      int4 A0 = *(const int4*)(base + (rg * 4 + ks * 2 + 0) * 1024 + lane * 16);
      int4 A1 = *(const int4*)(base + (rg * 4 + ks * 2 + 1) * 1024 + lane * 16);
      const float* sp = &s2s[c * 64 + ks * 32 + q * 8];
      float4 sv0 = *(const float4*)sp;
      float4 sv1 = *(const float4*)(sp + 4);
      float xs[8] = {sv0.x, sv0.y, sv0.z, sv0.w, sv1.x, sv1.y, sv1.z, sv1.w};
      int avs[8] = {A0.x, A0.y, A0.z, A0.w, A1.x, A1.y, A1.z, A1.w};
      f16x8 af;
#pragma unroll
      for (int j = 0; j < 8; ++j) {
        float x = s1r + xs[j];
        float e = fmaxf(x, LRELU_ALPHA * x);
        e = avs[j] ? (e - 2.0f) : NEG_INF;  // -2: fp16 range headroom
        float p = __expf(e);                // masked -> exactly 0.0f
        lsum += p;
        af[j] = (_Float16)p;
      }
      f16x8 b0 = *(const f16x8*)(base + (8 + (p0 + 0) * 2 + ks) * 1024 + lane * 16);
      f16x8 b1 = *(const f16x8*)(base + (8 + (p0 + 1) * 2 + ks) * 1024 + lane * 16);
      acc0 = __builtin_amdgcn_mfma_f32_16x16x32_f16(af, b0, acc0, 0, 0, 0);
      acc1 = __builtin_amdgcn_mfma_f32_16x16x32_f16(af, b1, acc1, 0, 0, 0);
    }
  };

  STAGE(sA, 0);
  __syncthreads();  // chunk 0 staged (barrier drains vmcnt) + s2s visible

  for (int cc = 0; cc < 16; ++cc) {
    const int c0 = 2 * cc, c1 = 2 * cc + 1;
    STAGE(sB, c1);       // DMA in flight during consume of sA
    consume(sA, c0);
    __syncthreads();     // drain sB staging; all waves done with sA
    if (c1 + 1 < 32) STAGE(sA, c1 + 1);
    consume(sB, c1);
    __syncthreads();
  }

  // row sums: reduce the 4 q-slices of row m
  lsum += __shfl_xor(lsum, 16, 64);
  lsum += __shfl_xor(lsum, 32, 64);
  if (wave < 2 && lane < 16) lsum_lds[wave * 16 + lane] = lsum;
  __syncthreads();

  // C/D layout: row_in_tile = q*4 + reg, col = m
#pragma unroll
  for (int r = 0; r < 4; ++r) {
    const int ri = q * 4 + r;
    float l = lsum_lds[rg * 16 + ri];
    float inv = (l == 0.f) ? 1.f : 1.f / l;  // fully-masked row guard
    const size_t row = (size_t)b * N_ + i0 + rg * 16 + ri;
    out[row * FOUT + (p0 + 0) * 16 + m] = acc0[r] * inv;
    out[row * FOUT + (p0 + 1) * 16 + m] = acc1[r] * inv;
  }
#undef STAGE
}

extern "C" void kernel_launch(void* const* d_in, const int* in_sizes, int n_in,
                              void* d_out, int out_size, void* d_ws, size_t ws_size,
                              hipStream_t stream) {
  const float* h   = (const float*)d_in[0];
  const int*   adj = (const int*)d_in[1];
  const float* W   = (const float*)d_in[2];
  const float* a   = (const float*)d_in[3];
  float* out = (float*)d_out;

  // ws: WhT fp16 (2 MB) | s1 (64 KB) | s2 (64 KB)
  unsigned short* WhT = (unsigned short*)d_ws;
  float* s1 = (float*)(WhT + (size_t)B_ * 64 * N_);
  float* s2 = s1 + (size_t)B_ * N_;

  k_wh<<<dim3(B_ * N_ / 16), 256, 0, stream>>>(h, W, a, WhT, s1, s2);
  k_attn<<<dim3(N_ / 32, B_), 256, 0, stream>>>(WhT, s1, s2, adj, out);
}